// Round 3
// baseline (554.338 us; speedup 1.0000x reference)
//
#include <hip/hip_runtime.h>

#define D 128
#define NLAYERS 4

// ---------------- CSR build ----------------

__global__ void k_count_deg(const int* __restrict__ dsts, int E, int* __restrict__ deg) {
    int i = blockIdx.x * blockDim.x + threadIdx.x;
    if (i < E) atomicAdd(&deg[dsts[i]], 1);
}

__global__ void k_dinv(const int* __restrict__ deg, int n, float* __restrict__ dinv) {
    int i = blockIdx.x * blockDim.x + threadIdx.x;
    if (i < n) dinv[i] = rsqrtf((float)(deg[i] + 1));  // +1 self-loop; always > 0
}

// exclusive scan of deg -> row_ptr. 1024 elems per 256-thread block.
__global__ void k_scan1(const int* __restrict__ deg, int n, int* __restrict__ out,
                        int* __restrict__ partials) {
    __shared__ int wsum[4];
    int tid = threadIdx.x;
    int base = blockIdx.x * 1024 + tid * 4;
    int d0 = (base + 0 < n) ? deg[base + 0] : 0;
    int d1 = (base + 1 < n) ? deg[base + 1] : 0;
    int d2 = (base + 2 < n) ? deg[base + 2] : 0;
    int d3 = (base + 3 < n) ? deg[base + 3] : 0;
    int s = d0 + d1 + d2 + d3;
    int lane = tid & 63;
    int incl = s;
    #pragma unroll
    for (int off = 1; off < 64; off <<= 1) {
        int y = __shfl_up(incl, off);
        if (lane >= off) incl += y;
    }
    int wid = tid >> 6;
    if (lane == 63) wsum[wid] = incl;
    __syncthreads();
    int wprev = 0;
    for (int w = 0; w < wid; w++) wprev += wsum[w];
    int excl = wprev + (incl - s);
    if (base + 0 < n) out[base + 0] = excl;
    if (base + 1 < n) out[base + 1] = excl + d0;
    if (base + 2 < n) out[base + 2] = excl + d0 + d1;
    if (base + 3 < n) out[base + 3] = excl + d0 + d1 + d2;
    if (tid == 255) partials[blockIdx.x] = wprev + incl;
}

__global__ void k_scan2(int* partials, int nb) {
    if (threadIdx.x == 0 && blockIdx.x == 0) {
        int acc = 0;
        for (int i = 0; i < nb; i++) { int t = partials[i]; partials[i] = acc; acc += t; }
    }
}

__global__ void k_scan3(int* __restrict__ row_ptr, const int* __restrict__ partials,
                        int n, int E) {
    int i = blockIdx.x * blockDim.x + threadIdx.x;
    if (i < n) row_ptr[i] += partials[i >> 10];
    if (i == 0) row_ptr[n] = E;
}

// place edges sorted by destination; pack (src, dinv[src]) in 8B
__global__ void k_place(const int* __restrict__ srcs, const int* __restrict__ dsts, int E,
                        const int* __restrict__ row_ptr, int* __restrict__ cursor,
                        const float* __restrict__ dinv, int2* __restrict__ ew) {
    int i = blockIdx.x * blockDim.x + threadIdx.x;
    if (i >= E) return;
    int c = dsts[i], r = srcs[i];
    int pos = row_ptr[c] + atomicAdd(&cursor[c], 1);
    int2 v;
    v.x = r;
    v.y = __float_as_int(dinv[r]);
    ew[pos] = v;
}

// ---------------- per-layer: aggregation s = A_norm * x ----------------
// one wave per node; lane holds 2 floats (float2 at lane offset -> 512B row read)
__global__ __launch_bounds__(256) void k_aggregate(
    const float* __restrict__ x, const int* __restrict__ row_ptr,
    const int2* __restrict__ ew, const float* __restrict__ dinv,
    float* __restrict__ s, int n) {
    int gwave = (blockIdx.x * 256 + threadIdx.x) >> 6;
    if (gwave >= n) return;
    int lane = threadIdx.x & 63;
    int node = gwave;
    float di = dinv[node];
    float2 self = ((const float2*)(x + (size_t)node * D))[lane];
    float acc0 = di * self.x;
    float acc1 = di * self.y;
    int e = row_ptr[node];
    int end = row_ptr[node + 1];
    for (; e + 2 <= end; e += 2) {
        int2 e0 = ew[e];
        int2 e1 = ew[e + 1];
        float2 v0 = ((const float2*)(x + (size_t)e0.x * D))[lane];
        float2 v1 = ((const float2*)(x + (size_t)e1.x * D))[lane];
        float w0 = __int_as_float(e0.y);
        float w1 = __int_as_float(e1.y);
        acc0 += w0 * v0.x + w1 * v1.x;
        acc1 += w0 * v0.y + w1 * v1.y;
    }
    if (e < end) {
        int2 e0 = ew[e];
        float2 v0 = ((const float2*)(x + (size_t)e0.x * D))[lane];
        float w0 = __int_as_float(e0.y);
        acc0 += w0 * v0.x;
        acc1 += w0 * v0.y;
    }
    float2 o;
    o.x = di * acc0;
    o.y = di * acc1;
    ((float2*)(s + (size_t)node * D))[lane] = o;
}

// ---------------- per-layer: out = relu(A @ W + b) ----------------
// 64 rows per block, A staged in LDS, W from L2; thread computes 8 rows x 4 cols
__global__ __launch_bounds__(256) void k_gemm_bias_relu(
    const float* __restrict__ A, const float* __restrict__ Wl,
    const float* __restrict__ bias, float* __restrict__ out, int n) {
    __shared__ float As[64][D];
    int tid = threadIdx.x;
    int brow = blockIdx.x * 64;
    #pragma unroll
    for (int p = 0; p < 8; p++) {
        int r = p * 8 + (tid >> 5);
        int c = (tid & 31) * 4;
        int gr = brow + r;
        if (gr > n - 1) gr = n - 1;  // clamp (values unused in guarded store)
        float4 v = *(const float4*)(A + (size_t)gr * D + c);
        *(float4*)&As[r][c] = v;
    }
    __syncthreads();
    int rg = tid >> 5;   // 0..7 -> rows rg*8..rg*8+7
    int cg = tid & 31;   // 0..31 -> cols cg*4..cg*4+3
    int c0 = cg * 4;
    float acc[8][4];
    #pragma unroll
    for (int j = 0; j < 8; j++)
        #pragma unroll
        for (int q = 0; q < 4; q++) acc[j][q] = 0.f;

    for (int k0 = 0; k0 < D; k0 += 4) {
        float4 w0 = *(const float4*)(Wl + (size_t)(k0 + 0) * D + c0);
        float4 w1 = *(const float4*)(Wl + (size_t)(k0 + 1) * D + c0);
        float4 w2 = *(const float4*)(Wl + (size_t)(k0 + 2) * D + c0);
        float4 w3 = *(const float4*)(Wl + (size_t)(k0 + 3) * D + c0);
        #pragma unroll
        for (int j = 0; j < 8; j++) {
            float4 a = *(const float4*)&As[rg * 8 + j][k0];
            acc[j][0] += a.x * w0.x + a.y * w1.x + a.z * w2.x + a.w * w3.x;
            acc[j][1] += a.x * w0.y + a.y * w1.y + a.z * w2.y + a.w * w3.y;
            acc[j][2] += a.x * w0.z + a.y * w1.z + a.z * w2.z + a.w * w3.z;
            acc[j][3] += a.x * w0.w + a.y * w1.w + a.z * w2.w + a.w * w3.w;
        }
    }
    float4 bv = *(const float4*)(bias + c0);
    #pragma unroll
    for (int j = 0; j < 8; j++) {
        int gr = brow + rg * 8 + j;
        if (gr < n) {
            float4 o;
            o.x = fmaxf(acc[j][0] + bv.x, 0.f);
            o.y = fmaxf(acc[j][1] + bv.y, 0.f);
            o.z = fmaxf(acc[j][2] + bv.z, 0.f);
            o.w = fmaxf(acc[j][3] + bv.w, 0.f);
            *(float4*)(out + (size_t)gr * D + c0) = o;
        }
    }
}

// ---------------- host launch ----------------

extern "C" void kernel_launch(void* const* d_in, const int* in_sizes, int n_in,
                              void* d_out, int out_size, void* d_ws, size_t ws_size,
                              hipStream_t stream) {
    const float* x   = (const float*)d_in[0];
    const int* eidx  = (const int*)d_in[1];
    const float* W   = (const float*)d_in[4];
    const float* b   = (const float*)d_in[5];
    float* out       = (float*)d_out;

    const int N = in_sizes[0] / D;
    const int E = in_sizes[1] / 2;
    const int* srcs = eidx;       // edge_index[0]
    const int* dsts = eidx + E;   // edge_index[1]

    // workspace carve-up (512B aligned)
    char* ws = (char*)d_ws;
    size_t off = 0;
    auto alloc = [&](size_t bytes) -> void* {
        void* p = ws + off;
        off = (off + bytes + 511) & ~(size_t)511;
        return p;
    };
    int*   deg      = (int*)alloc((size_t)N * 4);
    float* dinv     = (float*)alloc((size_t)N * 4);
    int*   row_ptr  = (int*)alloc((size_t)(N + 1) * 4);
    int*   cursor   = (int*)alloc((size_t)N * 4);
    int*   partials = (int*)alloc(256 * 4);
    int2*  ew       = (int2*)alloc((size_t)E * 8);
    float* s_buf    = (float*)alloc((size_t)N * D * 4);
    float* x_buf    = (float*)alloc((size_t)N * D * 4);
    (void)ws_size; (void)n_in; (void)out_size;

    hipMemsetAsync(deg, 0, (size_t)N * 4, stream);
    hipMemsetAsync(cursor, 0, (size_t)N * 4, stream);

    int tE = (E + 255) / 256;
    int tN = (N + 255) / 256;
    int nbScan = (N + 1023) / 1024;

    k_count_deg<<<tE, 256, 0, stream>>>(dsts, E, deg);
    k_dinv<<<tN, 256, 0, stream>>>(deg, N, dinv);
    k_scan1<<<nbScan, 256, 0, stream>>>(deg, N, row_ptr, partials);
    k_scan2<<<1, 64, 0, stream>>>(partials, nbScan);
    k_scan3<<<tN, 256, 0, stream>>>(row_ptr, partials, N, E);
    k_place<<<tE, 256, 0, stream>>>(srcs, dsts, E, row_ptr, cursor, dinv, ew);

    int aggBlocks = (N + 3) / 4;          // 4 waves (nodes) per 256-thread block
    int gemmBlocks = (N + 63) / 64;

    const float* xin = x;
    for (int l = 0; l < NLAYERS; l++) {
        k_aggregate<<<aggBlocks, 256, 0, stream>>>(xin, row_ptr, ew, dinv, s_buf, N);
        float* xout = (l == NLAYERS - 1) ? out : x_buf;
        k_gemm_bias_relu<<<gemmBlocks, 256, 0, stream>>>(
            s_buf, W + (size_t)l * D * D, b + (size_t)l * D, xout, N);
        xin = x_buf;
    }
}

// Round 4
// 543.340 us; speedup vs baseline: 1.0202x; 1.0202x over previous
//
#include <hip/hip_runtime.h>

#define D 128
#define NLAYERS 4

// ---------------- CSR build ----------------

// count degrees AND record each edge's slot within its destination's bucket
__global__ void k_count_deg(const int* __restrict__ dsts, int E,
                            int* __restrict__ deg, int* __restrict__ slot) {
    int i = blockIdx.x * blockDim.x + threadIdx.x;
    if (i < E) slot[i] = atomicAdd(&deg[dsts[i]], 1);
}

__global__ void k_dinv(const int* __restrict__ deg, int n, float* __restrict__ dinv) {
    int i = blockIdx.x * blockDim.x + threadIdx.x;
    if (i < n) dinv[i] = rsqrtf((float)(deg[i] + 1));  // +1 self-loop; always > 0
}

// exclusive scan of deg -> row_ptr. 1024 elems per 256-thread block.
__global__ void k_scan1(const int* __restrict__ deg, int n, int* __restrict__ out,
                        int* __restrict__ partials) {
    __shared__ int wsum[4];
    int tid = threadIdx.x;
    int base = blockIdx.x * 1024 + tid * 4;
    int d0 = (base + 0 < n) ? deg[base + 0] : 0;
    int d1 = (base + 1 < n) ? deg[base + 1] : 0;
    int d2 = (base + 2 < n) ? deg[base + 2] : 0;
    int d3 = (base + 3 < n) ? deg[base + 3] : 0;
    int s = d0 + d1 + d2 + d3;
    int lane = tid & 63;
    int incl = s;
    #pragma unroll
    for (int off = 1; off < 64; off <<= 1) {
        int y = __shfl_up(incl, off);
        if (lane >= off) incl += y;
    }
    int wid = tid >> 6;
    if (lane == 63) wsum[wid] = incl;
    __syncthreads();
    int wprev = 0;
    for (int w = 0; w < wid; w++) wprev += wsum[w];
    int excl = wprev + (incl - s);
    if (base + 0 < n) out[base + 0] = excl;
    if (base + 1 < n) out[base + 1] = excl + d0;
    if (base + 2 < n) out[base + 2] = excl + d0 + d1;
    if (base + 3 < n) out[base + 3] = excl + d0 + d1 + d2;
    if (tid == 255) partials[blockIdx.x] = wprev + incl;
}

__global__ void k_scan2(int* partials, int nb) {
    if (threadIdx.x == 0 && blockIdx.x == 0) {
        int acc = 0;
        for (int i = 0; i < nb; i++) { int t = partials[i]; partials[i] = acc; acc += t; }
    }
}

__global__ void k_scan3(int* __restrict__ row_ptr, const int* __restrict__ partials,
                        int n, int E) {
    int i = blockIdx.x * blockDim.x + threadIdx.x;
    if (i < n) row_ptr[i] += partials[i >> 10];
    if (i == 0) row_ptr[n] = E;
}

// place edges sorted by destination (atomic-free; slot precomputed)
__global__ void k_place(const int* __restrict__ srcs, const int* __restrict__ dsts, int E,
                        const int* __restrict__ row_ptr, const int* __restrict__ slot,
                        const float* __restrict__ dinv, int2* __restrict__ ew) {
    int i = blockIdx.x * blockDim.x + threadIdx.x;
    if (i >= E) return;
    int c = dsts[i], r = srcs[i];
    int pos = row_ptr[c] + slot[i];
    int2 v;
    v.x = r;
    v.y = __float_as_int(dinv[r]);
    ew[pos] = v;
}

// ---------------- fused layer: out = relu((A_norm @ x) @ W + b) ----------------
// 64 dst nodes per 256-thread block. Phase 1: each wave aggregates 16 nodes
// (one contiguous 512B row gather per edge, unroll 4) into LDS. Phase 2:
// 64x128 @ 128x128 GEMM from LDS (broadcast reads), W streamed from L2.
__global__ __launch_bounds__(256) void k_fused_layer(
    const float* __restrict__ x, const int* __restrict__ row_ptr,
    const int2* __restrict__ ew, const float* __restrict__ dinv,
    const float* __restrict__ Wl, const float* __restrict__ bias,
    float* __restrict__ out, int n) {
    __shared__ float As[64][D];
    int tid = threadIdx.x;
    int wid = tid >> 6;
    int lane = tid & 63;
    int brow = blockIdx.x * 64;

    // ---- phase 1: aggregate ----
    for (int m = 0; m < 16; ++m) {
        int r = wid * 16 + m;
        int node = brow + r;
        int nd = (node < n) ? node : (n - 1);  // clamp; extra rows never stored
        float di = dinv[nd];
        float2 self = ((const float2*)(x + (size_t)nd * D))[lane];
        float acc0 = di * self.x;
        float acc1 = di * self.y;
        int e = row_ptr[nd];
        int end = row_ptr[nd + 1];
        for (; e + 4 <= end; e += 4) {
            int2 e0 = ew[e];
            int2 e1 = ew[e + 1];
            int2 e2 = ew[e + 2];
            int2 e3 = ew[e + 3];
            float2 v0 = ((const float2*)(x + (size_t)e0.x * D))[lane];
            float2 v1 = ((const float2*)(x + (size_t)e1.x * D))[lane];
            float2 v2 = ((const float2*)(x + (size_t)e2.x * D))[lane];
            float2 v3 = ((const float2*)(x + (size_t)e3.x * D))[lane];
            float w0 = __int_as_float(e0.y), w1 = __int_as_float(e1.y);
            float w2 = __int_as_float(e2.y), w3 = __int_as_float(e3.y);
            acc0 += w0 * v0.x + w1 * v1.x + w2 * v2.x + w3 * v3.x;
            acc1 += w0 * v0.y + w1 * v1.y + w2 * v2.y + w3 * v3.y;
        }
        for (; e < end; ++e) {
            int2 e0 = ew[e];
            float2 v0 = ((const float2*)(x + (size_t)e0.x * D))[lane];
            float w0 = __int_as_float(e0.y);
            acc0 += w0 * v0.x;
            acc1 += w0 * v0.y;
        }
        float2 o;
        o.x = di * acc0;
        o.y = di * acc1;
        ((float2*)As[r])[lane] = o;
    }
    __syncthreads();

    // ---- phase 2: GEMM + bias + relu ----
    int rg = tid >> 5;   // 0..7 -> rows rg*8..rg*8+7
    int cg = tid & 31;   // 0..31 -> cols cg*4..cg*4+3
    int c0 = cg * 4;
    float acc[8][4];
    #pragma unroll
    for (int j = 0; j < 8; j++)
        #pragma unroll
        for (int q = 0; q < 4; q++) acc[j][q] = 0.f;

    for (int k0 = 0; k0 < D; k0 += 4) {
        float4 w0 = *(const float4*)(Wl + (size_t)(k0 + 0) * D + c0);
        float4 w1 = *(const float4*)(Wl + (size_t)(k0 + 1) * D + c0);
        float4 w2 = *(const float4*)(Wl + (size_t)(k0 + 2) * D + c0);
        float4 w3 = *(const float4*)(Wl + (size_t)(k0 + 3) * D + c0);
        #pragma unroll
        for (int j = 0; j < 8; j++) {
            float4 a = *(const float4*)&As[rg * 8 + j][k0];
            acc[j][0] += a.x * w0.x + a.y * w1.x + a.z * w2.x + a.w * w3.x;
            acc[j][1] += a.x * w0.y + a.y * w1.y + a.z * w2.y + a.w * w3.y;
            acc[j][2] += a.x * w0.z + a.y * w1.z + a.z * w2.z + a.w * w3.z;
            acc[j][3] += a.x * w0.w + a.y * w1.w + a.z * w2.w + a.w * w3.w;
        }
    }
    float4 bv = *(const float4*)(bias + c0);
    #pragma unroll
    for (int j = 0; j < 8; j++) {
        int gr = brow + rg * 8 + j;
        if (gr < n) {
            float4 o;
            o.x = fmaxf(acc[j][0] + bv.x, 0.f);
            o.y = fmaxf(acc[j][1] + bv.y, 0.f);
            o.z = fmaxf(acc[j][2] + bv.z, 0.f);
            o.w = fmaxf(acc[j][3] + bv.w, 0.f);
            *(float4*)(out + (size_t)gr * D + c0) = o;
        }
    }
}

// ---------------- host launch ----------------

extern "C" void kernel_launch(void* const* d_in, const int* in_sizes, int n_in,
                              void* d_out, int out_size, void* d_ws, size_t ws_size,
                              hipStream_t stream) {
    const float* x   = (const float*)d_in[0];
    const int* eidx  = (const int*)d_in[1];
    const float* W   = (const float*)d_in[4];
    const float* b   = (const float*)d_in[5];
    float* out       = (float*)d_out;

    const int N = in_sizes[0] / D;
    const int E = in_sizes[1] / 2;
    const int* srcs = eidx;       // edge_index[0]
    const int* dsts = eidx + E;   // edge_index[1]

    // workspace carve-up (512B aligned)
    char* ws = (char*)d_ws;
    size_t off = 0;
    auto alloc = [&](size_t bytes) -> void* {
        void* p = ws + off;
        off = (off + bytes + 511) & ~(size_t)511;
        return p;
    };
    int*   deg      = (int*)alloc((size_t)N * 4);
    float* dinv     = (float*)alloc((size_t)N * 4);
    int*   row_ptr  = (int*)alloc((size_t)(N + 1) * 4);
    int*   partials = (int*)alloc(256 * 4);
    int2*  ew       = (int2*)alloc((size_t)E * 8);
    float* xa       = (float*)alloc((size_t)N * D * 4);
    float* xb       = (float*)alloc((size_t)N * D * 4);
    // slot[] is only live during CSR build, before any layer writes xa
    int*   slot     = (int*)xa;
    (void)ws_size; (void)n_in; (void)out_size;

    hipMemsetAsync(deg, 0, (size_t)N * 4, stream);

    int tE = (E + 255) / 256;
    int tN = (N + 255) / 256;
    int nbScan = (N + 1023) / 1024;

    k_count_deg<<<tE, 256, 0, stream>>>(dsts, E, deg, slot);
    k_dinv<<<tN, 256, 0, stream>>>(deg, N, dinv);
    k_scan1<<<nbScan, 256, 0, stream>>>(deg, N, row_ptr, partials);
    k_scan2<<<1, 64, 0, stream>>>(partials, nbScan);
    k_scan3<<<tN, 256, 0, stream>>>(row_ptr, partials, N, E);
    k_place<<<tE, 256, 0, stream>>>(srcs, dsts, E, row_ptr, slot, dinv, ew);

    int fusedBlocks = (N + 63) / 64;

    // ping-pong: x -> xa -> xb -> xa -> out
    const float* xin = x;
    for (int l = 0; l < NLAYERS; l++) {
        float* xout = (l == NLAYERS - 1) ? out : ((l & 1) ? xb : xa);
        k_fused_layer<<<fusedBlocks, 256, 0, stream>>>(
            xin, row_ptr, ew, dinv, W + (size_t)l * D * D, b + (size_t)l * D, xout, N);
        xin = xout;
    }
}

// Round 5
// 443.315 us; speedup vs baseline: 1.2504x; 1.2256x over previous
//
#include <hip/hip_runtime.h>

#define D 128
#define NLAYERS 4

typedef unsigned short ushort_t;
typedef unsigned int uint_t;

// round-to-nearest-even fp32 -> bf16 (values are finite; NaN path not needed)
__device__ __forceinline__ ushort_t f2bf(float f) {
    uint_t u = __float_as_uint(f);
    u += 0x7FFFu + ((u >> 16) & 1u);
    return (ushort_t)(u >> 16);
}
__device__ __forceinline__ float bf_lo(uint_t u) {  // low ushort -> float
    return __uint_as_float(u << 16);
}
__device__ __forceinline__ float bf_hi(uint_t u) {  // high ushort -> float
    return __uint_as_float(u & 0xFFFF0000u);
}

// ---------------- CSR build ----------------

// count degrees AND record each edge's slot within its destination's bucket
__global__ void k_count_deg(const int* __restrict__ dsts, int E,
                            int* __restrict__ deg, int* __restrict__ slot) {
    int i = blockIdx.x * blockDim.x + threadIdx.x;
    if (i < E) slot[i] = atomicAdd(&deg[dsts[i]], 1);
}

__global__ void k_dinv(const int* __restrict__ deg, int n, float* __restrict__ dinv) {
    int i = blockIdx.x * blockDim.x + threadIdx.x;
    if (i < n) dinv[i] = rsqrtf((float)(deg[i] + 1));  // +1 self-loop; always > 0
}

// exclusive scan of deg -> row_ptr. 1024 elems per 256-thread block.
__global__ void k_scan1(const int* __restrict__ deg, int n, int* __restrict__ out,
                        int* __restrict__ partials) {
    __shared__ int wsum[4];
    int tid = threadIdx.x;
    int base = blockIdx.x * 1024 + tid * 4;
    int d0 = (base + 0 < n) ? deg[base + 0] : 0;
    int d1 = (base + 1 < n) ? deg[base + 1] : 0;
    int d2 = (base + 2 < n) ? deg[base + 2] : 0;
    int d3 = (base + 3 < n) ? deg[base + 3] : 0;
    int s = d0 + d1 + d2 + d3;
    int lane = tid & 63;
    int incl = s;
    #pragma unroll
    for (int off = 1; off < 64; off <<= 1) {
        int y = __shfl_up(incl, off);
        if (lane >= off) incl += y;
    }
    int wid = tid >> 6;
    if (lane == 63) wsum[wid] = incl;
    __syncthreads();
    int wprev = 0;
    for (int w = 0; w < wid; w++) wprev += wsum[w];
    int excl = wprev + (incl - s);
    if (base + 0 < n) out[base + 0] = excl;
    if (base + 1 < n) out[base + 1] = excl + d0;
    if (base + 2 < n) out[base + 2] = excl + d0 + d1;
    if (base + 3 < n) out[base + 3] = excl + d0 + d1 + d2;
    if (tid == 255) partials[blockIdx.x] = wprev + incl;
}

__global__ void k_scan2(int* partials, int nb) {
    if (threadIdx.x == 0 && blockIdx.x == 0) {
        int acc = 0;
        for (int i = 0; i < nb; i++) { int t = partials[i]; partials[i] = acc; acc += t; }
    }
}

__global__ void k_scan3(int* __restrict__ row_ptr, const int* __restrict__ partials,
                        int n, int E) {
    int i = blockIdx.x * blockDim.x + threadIdx.x;
    if (i < n) row_ptr[i] += partials[i >> 10];
    if (i == 0) row_ptr[n] = E;
}

// place edges sorted by destination (atomic-free; slot precomputed)
__global__ void k_place(const int* __restrict__ srcs, const int* __restrict__ dsts, int E,
                        const int* __restrict__ row_ptr, const int* __restrict__ slot,
                        const float* __restrict__ dinv, int2* __restrict__ ew) {
    int i = blockIdx.x * blockDim.x + threadIdx.x;
    if (i >= E) return;
    int c = dsts[i], r = srcs[i];
    int pos = row_ptr[c] + slot[i];
    int2 v;
    v.x = r;
    v.y = __float_as_int(dinv[r]);
    ew[pos] = v;
}

// ---------------- x (fp32) -> bf16 ----------------
__global__ void k_tobf16(const float* __restrict__ x, ushort_t* __restrict__ xh,
                         int total4) {
    int i = blockIdx.x * blockDim.x + threadIdx.x;
    if (i >= total4) return;
    float4 v = ((const float4*)x)[i];
    ushort_t r0 = f2bf(v.x), r1 = f2bf(v.y), r2 = f2bf(v.z), r3 = f2bf(v.w);
    uint2 o;
    o.x = (uint_t)r0 | ((uint_t)r1 << 16);
    o.y = (uint_t)r2 | ((uint_t)r3 << 16);
    ((uint2*)xh)[i] = o;
}

// ---------------- per-layer: aggregation s = A_norm * x  (bf16 rows) ----------------
// one wave per node; lane reads one dword = 2 bf16 (256B/row, coalesced)
__global__ __launch_bounds__(256) void k_aggregate(
    const ushort_t* __restrict__ xh, const int* __restrict__ row_ptr,
    const int2* __restrict__ ew, const float* __restrict__ dinv,
    float* __restrict__ s, int n) {
    int gwave = (blockIdx.x * 256 + threadIdx.x) >> 6;
    if (gwave >= n) return;
    int lane = threadIdx.x & 63;
    int node = gwave;
    float di = dinv[node];
    uint_t su = *(const uint_t*)(xh + (size_t)node * D + 2 * lane);
    float acc0 = di * bf_lo(su);
    float acc1 = di * bf_hi(su);
    int e = row_ptr[node];
    int end = row_ptr[node + 1];
    for (; e + 4 <= end; e += 4) {
        int2 e0 = ew[e];
        int2 e1 = ew[e + 1];
        int2 e2 = ew[e + 2];
        int2 e3 = ew[e + 3];
        uint_t u0 = *(const uint_t*)(xh + (size_t)e0.x * D + 2 * lane);
        uint_t u1 = *(const uint_t*)(xh + (size_t)e1.x * D + 2 * lane);
        uint_t u2 = *(const uint_t*)(xh + (size_t)e2.x * D + 2 * lane);
        uint_t u3 = *(const uint_t*)(xh + (size_t)e3.x * D + 2 * lane);
        float w0 = __int_as_float(e0.y), w1 = __int_as_float(e1.y);
        float w2 = __int_as_float(e2.y), w3 = __int_as_float(e3.y);
        acc0 += w0 * bf_lo(u0) + w1 * bf_lo(u1) + w2 * bf_lo(u2) + w3 * bf_lo(u3);
        acc1 += w0 * bf_hi(u0) + w1 * bf_hi(u1) + w2 * bf_hi(u2) + w3 * bf_hi(u3);
    }
    for (; e < end; ++e) {
        int2 e0 = ew[e];
        uint_t u0 = *(const uint_t*)(xh + (size_t)e0.x * D + 2 * lane);
        float w0 = __int_as_float(e0.y);
        acc0 += w0 * bf_lo(u0);
        acc1 += w0 * bf_hi(u0);
    }
    float2 o;
    o.x = di * acc0;
    o.y = di * acc1;
    ((float2*)(s + (size_t)node * D))[lane] = o;
}

// ---------------- per-layer: out = relu(A @ W + b) ----------------
// 64 rows per block, A staged in LDS, W from L2; thread computes 8 rows x 4 cols.
// Writes bf16 (next layer's gather input) if out_bf != nullptr, else fp32.
__global__ __launch_bounds__(256) void k_gemm_bias_relu(
    const float* __restrict__ A, const float* __restrict__ Wl,
    const float* __restrict__ bias, float* __restrict__ out_f32,
    ushort_t* __restrict__ out_bf, int n) {
    __shared__ float As[64][D];
    int tid = threadIdx.x;
    int brow = blockIdx.x * 64;
    #pragma unroll
    for (int p = 0; p < 8; p++) {
        int r = p * 8 + (tid >> 5);
        int c = (tid & 31) * 4;
        int gr = brow + r;
        if (gr > n - 1) gr = n - 1;  // clamp (values unused in guarded store)
        float4 v = *(const float4*)(A + (size_t)gr * D + c);
        *(float4*)&As[r][c] = v;
    }
    __syncthreads();
    int rg = tid >> 5;   // 0..7 -> rows rg*8..rg*8+7
    int cg = tid & 31;   // 0..31 -> cols cg*4..cg*4+3
    int c0 = cg * 4;
    float acc[8][4];
    #pragma unroll
    for (int j = 0; j < 8; j++)
        #pragma unroll
        for (int q = 0; q < 4; q++) acc[j][q] = 0.f;

    for (int k0 = 0; k0 < D; k0 += 4) {
        float4 w0 = *(const float4*)(Wl + (size_t)(k0 + 0) * D + c0);
        float4 w1 = *(const float4*)(Wl + (size_t)(k0 + 1) * D + c0);
        float4 w2 = *(const float4*)(Wl + (size_t)(k0 + 2) * D + c0);
        float4 w3 = *(const float4*)(Wl + (size_t)(k0 + 3) * D + c0);
        #pragma unroll
        for (int j = 0; j < 8; j++) {
            float4 a = *(const float4*)&As[rg * 8 + j][k0];
            acc[j][0] += a.x * w0.x + a.y * w1.x + a.z * w2.x + a.w * w3.x;
            acc[j][1] += a.x * w0.y + a.y * w1.y + a.z * w2.y + a.w * w3.y;
            acc[j][2] += a.x * w0.z + a.y * w1.z + a.z * w2.z + a.w * w3.z;
            acc[j][3] += a.x * w0.w + a.y * w1.w + a.z * w2.w + a.w * w3.w;
        }
    }
    float4 bv = *(const float4*)(bias + c0);
    #pragma unroll
    for (int j = 0; j < 8; j++) {
        int gr = brow + rg * 8 + j;
        if (gr < n) {
            float o0 = fmaxf(acc[j][0] + bv.x, 0.f);
            float o1 = fmaxf(acc[j][1] + bv.y, 0.f);
            float o2 = fmaxf(acc[j][2] + bv.z, 0.f);
            float o3 = fmaxf(acc[j][3] + bv.w, 0.f);
            if (out_bf) {
                uint2 o;
                o.x = (uint_t)f2bf(o0) | ((uint_t)f2bf(o1) << 16);
                o.y = (uint_t)f2bf(o2) | ((uint_t)f2bf(o3) << 16);
                *(uint2*)(out_bf + (size_t)gr * D + c0) = o;
            } else {
                float4 o;
                o.x = o0; o.y = o1; o.z = o2; o.w = o3;
                *(float4*)(out_f32 + (size_t)gr * D + c0) = o;
            }
        }
    }
}

// ---------------- host launch ----------------

extern "C" void kernel_launch(void* const* d_in, const int* in_sizes, int n_in,
                              void* d_out, int out_size, void* d_ws, size_t ws_size,
                              hipStream_t stream) {
    const float* x   = (const float*)d_in[0];
    const int* eidx  = (const int*)d_in[1];
    const float* W   = (const float*)d_in[4];
    const float* b   = (const float*)d_in[5];
    float* out       = (float*)d_out;

    const int N = in_sizes[0] / D;
    const int E = in_sizes[1] / 2;
    const int* srcs = eidx;       // edge_index[0]
    const int* dsts = eidx + E;   // edge_index[1]

    // workspace carve-up (512B aligned)
    char* ws = (char*)d_ws;
    size_t off = 0;
    auto alloc = [&](size_t bytes) -> void* {
        void* p = ws + off;
        off = (off + bytes + 511) & ~(size_t)511;
        return p;
    };
    int*      deg      = (int*)alloc((size_t)N * 4);
    float*    dinv     = (float*)alloc((size_t)N * 4);
    int*      row_ptr  = (int*)alloc((size_t)(N + 1) * 4);
    int*      partials = (int*)alloc(256 * 4);
    int2*     ew       = (int2*)alloc((size_t)E * 8);
    float*    s_buf    = (float*)alloc((size_t)N * D * 4);
    ushort_t* xh0      = (ushort_t*)alloc((size_t)N * D * 2);
    ushort_t* xh1      = (ushort_t*)alloc((size_t)N * D * 2);
    // slot[] only live during CSR build, before first aggregate writes s_buf
    int*      slot     = (int*)s_buf;
    (void)ws_size; (void)n_in; (void)out_size;

    hipMemsetAsync(deg, 0, (size_t)N * 4, stream);

    int tE = (E + 255) / 256;
    int tN = (N + 255) / 256;
    int nbScan = (N + 1023) / 1024;

    k_count_deg<<<tE, 256, 0, stream>>>(dsts, E, deg, slot);
    k_dinv<<<tN, 256, 0, stream>>>(deg, N, dinv);
    k_scan1<<<nbScan, 256, 0, stream>>>(deg, N, row_ptr, partials);
    k_scan2<<<1, 64, 0, stream>>>(partials, nbScan);
    k_scan3<<<tN, 256, 0, stream>>>(row_ptr, partials, N, E);
    k_place<<<tE, 256, 0, stream>>>(srcs, dsts, E, row_ptr, slot, dinv, ew);

    int total4 = N * D / 4;
    k_tobf16<<<(total4 + 255) / 256, 256, 0, stream>>>(x, xh0, total4);

    int aggBlocks = (N + 3) / 4;          // 4 waves (nodes) per 256-thread block
    int gemmBlocks = (N + 63) / 64;

    // activations ping-pong in bf16: xh0 -> xh1 -> xh0 -> xh1; final layer fp32 -> out
    const ushort_t* xin = xh0;
    for (int l = 0; l < NLAYERS; l++) {
        k_aggregate<<<aggBlocks, 256, 0, stream>>>(xin, row_ptr, ew, dinv, s_buf, N);
        bool last = (l == NLAYERS - 1);
        ushort_t* xout = last ? nullptr : ((l & 1) ? xh0 : xh1);
        k_gemm_bias_relu<<<gemmBlocks, 256, 0, stream>>>(
            s_buf, W + (size_t)l * D * D, b + (size_t)l * D,
            last ? out : nullptr, xout, N);
        xin = xout;
    }
}

// Round 6
// 416.079 us; speedup vs baseline: 1.3323x; 1.0655x over previous
//
#include <hip/hip_runtime.h>

#define D 128
#define NLAYERS 4

typedef unsigned short ushort_t;
typedef unsigned int uint_t;

// round-to-nearest-even fp32 -> bf16 (values are finite; NaN path not needed)
__device__ __forceinline__ ushort_t f2bf(float f) {
    uint_t u = __float_as_uint(f);
    u += 0x7FFFu + ((u >> 16) & 1u);
    return (ushort_t)(u >> 16);
}
__device__ __forceinline__ float bf_lo(uint_t u) {  // low ushort -> float
    return __uint_as_float(u << 16);
}
__device__ __forceinline__ float bf_hi(uint_t u) {  // high ushort -> float
    return __uint_as_float(u & 0xFFFF0000u);
}

// ---------------- CSR build ----------------

// count degrees AND record each edge's slot within its destination's bucket
__global__ void k_count_deg(const int* __restrict__ dsts, int E,
                            int* __restrict__ deg, int* __restrict__ slot) {
    int i = blockIdx.x * blockDim.x + threadIdx.x;
    if (i < E) slot[i] = atomicAdd(&deg[dsts[i]], 1);
}

// exclusive scan of deg -> row_ptr (1024/block) + dinv computation (fused)
__global__ void k_scan1(const int* __restrict__ deg, int n, int* __restrict__ out,
                        int* __restrict__ partials, float* __restrict__ dinv) {
    __shared__ int wsum[4];
    int tid = threadIdx.x;
    int base = blockIdx.x * 1024 + tid * 4;
    int d0 = (base + 0 < n) ? deg[base + 0] : 0;
    int d1 = (base + 1 < n) ? deg[base + 1] : 0;
    int d2 = (base + 2 < n) ? deg[base + 2] : 0;
    int d3 = (base + 3 < n) ? deg[base + 3] : 0;
    // dinv = rsqrt(deg+1) (+1 self-loop; always > 0)
    if (base + 0 < n) dinv[base + 0] = rsqrtf((float)(d0 + 1));
    if (base + 1 < n) dinv[base + 1] = rsqrtf((float)(d1 + 1));
    if (base + 2 < n) dinv[base + 2] = rsqrtf((float)(d2 + 1));
    if (base + 3 < n) dinv[base + 3] = rsqrtf((float)(d3 + 1));
    int s = d0 + d1 + d2 + d3;
    int lane = tid & 63;
    int incl = s;
    #pragma unroll
    for (int off = 1; off < 64; off <<= 1) {
        int y = __shfl_up(incl, off);
        if (lane >= off) incl += y;
    }
    int wid = tid >> 6;
    if (lane == 63) wsum[wid] = incl;
    __syncthreads();
    int wprev = 0;
    for (int w = 0; w < wid; w++) wprev += wsum[w];
    int excl = wprev + (incl - s);
    if (base + 0 < n) out[base + 0] = excl;
    if (base + 1 < n) out[base + 1] = excl + d0;
    if (base + 2 < n) out[base + 2] = excl + d0 + d1;
    if (base + 3 < n) out[base + 3] = excl + d0 + d1 + d2;
    if (tid == 255) partials[blockIdx.x] = wprev + incl;
}

__global__ void k_scan2(int* partials, int nb) {
    if (threadIdx.x == 0 && blockIdx.x == 0) {
        int acc = 0;
        for (int i = 0; i < nb; i++) { int t = partials[i]; partials[i] = acc; acc += t; }
    }
}

__global__ void k_scan3(int* __restrict__ row_ptr, const int* __restrict__ partials,
                        int n, int E) {
    int i = blockIdx.x * blockDim.x + threadIdx.x;
    if (i < n) row_ptr[i] += partials[i >> 10];
    if (i == 0) row_ptr[n] = E;
}

// place edges sorted by destination (atomic-free; slot precomputed)
__global__ void k_place(const int* __restrict__ srcs, const int* __restrict__ dsts, int E,
                        const int* __restrict__ row_ptr, const int* __restrict__ slot,
                        const float* __restrict__ dinv, int2* __restrict__ ew) {
    int i = blockIdx.x * blockDim.x + threadIdx.x;
    if (i >= E) return;
    int c = dsts[i], r = srcs[i];
    int pos = row_ptr[c] + slot[i];
    int2 v;
    v.x = r;
    v.y = __float_as_int(dinv[r]);
    ew[pos] = v;
}

// ---------------- x (fp32) -> bf16 ----------------
__global__ void k_tobf16(const float* __restrict__ x, ushort_t* __restrict__ xh,
                         int total4) {
    int i = blockIdx.x * blockDim.x + threadIdx.x;
    if (i >= total4) return;
    float4 v = ((const float4*)x)[i];
    uint2 o;
    o.x = (uint_t)f2bf(v.x) | ((uint_t)f2bf(v.y) << 16);
    o.y = (uint_t)f2bf(v.z) | ((uint_t)f2bf(v.w) << 16);
    ((uint2*)xh)[i] = o;
}

// ---------------- per-layer: aggregation s = A_norm * x  (bf16 rows) ----------------
// one wave per node; 4 edges per load instruction: lane l reads uint4 (16B)
// of edge slot sub=l>>4 at columns t=(l&15)*8. 8 fp32 accumulators per lane,
// cross-slot combine via shfl_xor(16/32) at the end.
__global__ __launch_bounds__(256) void k_aggregate(
    const ushort_t* __restrict__ xh, const int* __restrict__ row_ptr,
    const int2* __restrict__ ew, const float* __restrict__ dinv,
    float* __restrict__ s, int n) {
    int gwave = (blockIdx.x * 256 + threadIdx.x) >> 6;
    if (gwave >= n) return;
    int lane = threadIdx.x & 63;
    int sub = lane >> 4;   // edge slot within group of 4
    int t = lane & 15;     // column group: owns 8 bf16 cols starting at t*8
    int node = gwave;
    float di = dinv[node];

    float acc[8];
    {   // self contribution (weight di, only counted once via sub==0)
        uint4 v = *(const uint4*)(xh + (size_t)node * D + t * 8);
        float w = (sub == 0) ? di : 0.f;
        acc[0] = w * bf_lo(v.x); acc[1] = w * bf_hi(v.x);
        acc[2] = w * bf_lo(v.y); acc[3] = w * bf_hi(v.y);
        acc[4] = w * bf_lo(v.z); acc[5] = w * bf_hi(v.z);
        acc[6] = w * bf_lo(v.w); acc[7] = w * bf_hi(v.w);
    }
    int e = row_ptr[node], end = row_ptr[node + 1];
    // main loop: 8 edges (2 groups) per iteration, 2 gathers in flight
    for (; e + 8 <= end; e += 8) {
        int2 g0 = ew[e + sub];
        int2 g1 = ew[e + 4 + sub];
        uint4 v0 = *(const uint4*)(xh + (size_t)g0.x * D + t * 8);
        uint4 v1 = *(const uint4*)(xh + (size_t)g1.x * D + t * 8);
        float w0 = __int_as_float(g0.y);
        float w1 = __int_as_float(g1.y);
        acc[0] += w0 * bf_lo(v0.x); acc[1] += w0 * bf_hi(v0.x);
        acc[2] += w0 * bf_lo(v0.y); acc[3] += w0 * bf_hi(v0.y);
        acc[4] += w0 * bf_lo(v0.z); acc[5] += w0 * bf_hi(v0.z);
        acc[6] += w0 * bf_lo(v0.w); acc[7] += w0 * bf_hi(v0.w);
        acc[0] += w1 * bf_lo(v1.x); acc[1] += w1 * bf_hi(v1.x);
        acc[2] += w1 * bf_lo(v1.y); acc[3] += w1 * bf_hi(v1.y);
        acc[4] += w1 * bf_lo(v1.z); acc[5] += w1 * bf_hi(v1.z);
        acc[6] += w1 * bf_lo(v1.w); acc[7] += w1 * bf_hi(v1.w);
    }
    // tail: 1 group (up to 4 edges) per iteration
    for (; e < end; e += 4) {
        int rem = end - e;                      // >= 1
        int k = (sub < rem) ? sub : 0;          // clamp to a valid edge
        int2 g = ew[e + k];
        float w = (sub < rem) ? __int_as_float(g.y) : 0.f;
        uint4 v = *(const uint4*)(xh + (size_t)g.x * D + t * 8);
        acc[0] += w * bf_lo(v.x); acc[1] += w * bf_hi(v.x);
        acc[2] += w * bf_lo(v.y); acc[3] += w * bf_hi(v.y);
        acc[4] += w * bf_lo(v.z); acc[5] += w * bf_hi(v.z);
        acc[6] += w * bf_lo(v.w); acc[7] += w * bf_hi(v.w);
    }
    // combine the 4 edge slots
    #pragma unroll
    for (int q = 0; q < 8; q++) {
        acc[q] += __shfl_xor(acc[q], 16);
        acc[q] += __shfl_xor(acc[q], 32);
    }
    if (sub == 0) {
        float* dst = s + (size_t)node * D + t * 8;
        float4 o0, o1;
        o0.x = di * acc[0]; o0.y = di * acc[1]; o0.z = di * acc[2]; o0.w = di * acc[3];
        o1.x = di * acc[4]; o1.y = di * acc[5]; o1.z = di * acc[6]; o1.w = di * acc[7];
        *(float4*)dst = o0;
        *(float4*)(dst + 4) = o1;
    }
}

// ---------------- per-layer: out = relu(A @ W + b) ----------------
// 64 rows per block, A staged in LDS, W from L2; thread computes 8 rows x 4 cols.
// Writes bf16 (next layer's gather input) if out_bf != nullptr, else fp32.
__global__ __launch_bounds__(256) void k_gemm_bias_relu(
    const float* __restrict__ A, const float* __restrict__ Wl,
    const float* __restrict__ bias, float* __restrict__ out_f32,
    ushort_t* __restrict__ out_bf, int n) {
    __shared__ float As[64][D];
    int tid = threadIdx.x;
    int brow = blockIdx.x * 64;
    #pragma unroll
    for (int p = 0; p < 8; p++) {
        int r = p * 8 + (tid >> 5);
        int c = (tid & 31) * 4;
        int gr = brow + r;
        if (gr > n - 1) gr = n - 1;  // clamp (values unused in guarded store)
        float4 v = *(const float4*)(A + (size_t)gr * D + c);
        *(float4*)&As[r][c] = v;
    }
    __syncthreads();
    int rg = tid >> 5;   // 0..7 -> rows rg*8..rg*8+7
    int cg = tid & 31;   // 0..31 -> cols cg*4..cg*4+3
    int c0 = cg * 4;
    float acc[8][4];
    #pragma unroll
    for (int j = 0; j < 8; j++)
        #pragma unroll
        for (int q = 0; q < 4; q++) acc[j][q] = 0.f;

    for (int k0 = 0; k0 < D; k0 += 4) {
        float4 w0 = *(const float4*)(Wl + (size_t)(k0 + 0) * D + c0);
        float4 w1 = *(const float4*)(Wl + (size_t)(k0 + 1) * D + c0);
        float4 w2 = *(const float4*)(Wl + (size_t)(k0 + 2) * D + c0);
        float4 w3 = *(const float4*)(Wl + (size_t)(k0 + 3) * D + c0);
        #pragma unroll
        for (int j = 0; j < 8; j++) {
            float4 a = *(const float4*)&As[rg * 8 + j][k0];
            acc[j][0] += a.x * w0.x + a.y * w1.x + a.z * w2.x + a.w * w3.x;
            acc[j][1] += a.x * w0.y + a.y * w1.y + a.z * w2.y + a.w * w3.y;
            acc[j][2] += a.x * w0.z + a.y * w1.z + a.z * w2.z + a.w * w3.z;
            acc[j][3] += a.x * w0.w + a.y * w1.w + a.z * w2.w + a.w * w3.w;
        }
    }
    float4 bv = *(const float4*)(bias + c0);
    #pragma unroll
    for (int j = 0; j < 8; j++) {
        int gr = brow + rg * 8 + j;
        if (gr < n) {
            float o0 = fmaxf(acc[j][0] + bv.x, 0.f);
            float o1 = fmaxf(acc[j][1] + bv.y, 0.f);
            float o2 = fmaxf(acc[j][2] + bv.z, 0.f);
            float o3 = fmaxf(acc[j][3] + bv.w, 0.f);
            if (out_bf) {
                uint2 o;
                o.x = (uint_t)f2bf(o0) | ((uint_t)f2bf(o1) << 16);
                o.y = (uint_t)f2bf(o2) | ((uint_t)f2bf(o3) << 16);
                *(uint2*)(out_bf + (size_t)gr * D + c0) = o;
            } else {
                float4 o;
                o.x = o0; o.y = o1; o.z = o2; o.w = o3;
                *(float4*)(out_f32 + (size_t)gr * D + c0) = o;
            }
        }
    }
}

// ---------------- host launch ----------------

extern "C" void kernel_launch(void* const* d_in, const int* in_sizes, int n_in,
                              void* d_out, int out_size, void* d_ws, size_t ws_size,
                              hipStream_t stream) {
    const float* x   = (const float*)d_in[0];
    const int* eidx  = (const int*)d_in[1];
    const float* W   = (const float*)d_in[4];
    const float* b   = (const float*)d_in[5];
    float* out       = (float*)d_out;

    const int N = in_sizes[0] / D;
    const int E = in_sizes[1] / 2;
    const int* srcs = eidx;       // edge_index[0]
    const int* dsts = eidx + E;   // edge_index[1]

    // workspace carve-up (512B aligned)
    char* ws = (char*)d_ws;
    size_t off = 0;
    auto alloc = [&](size_t bytes) -> void* {
        void* p = ws + off;
        off = (off + bytes + 511) & ~(size_t)511;
        return p;
    };
    int*      deg      = (int*)alloc((size_t)N * 4);
    float*    dinv     = (float*)alloc((size_t)N * 4);
    int*      row_ptr  = (int*)alloc((size_t)(N + 1) * 4);
    int*      partials = (int*)alloc(256 * 4);
    int2*     ew       = (int2*)alloc((size_t)E * 8);
    float*    s_buf    = (float*)alloc((size_t)N * D * 4);
    ushort_t* xh0      = (ushort_t*)alloc((size_t)N * D * 2);
    ushort_t* xh1      = (ushort_t*)alloc((size_t)N * D * 2);
    // slot[] only live during CSR build, before first aggregate writes s_buf
    int*      slot     = (int*)s_buf;
    (void)ws_size; (void)n_in; (void)out_size;

    hipMemsetAsync(deg, 0, (size_t)N * 4, stream);

    int tE = (E + 255) / 256;
    int tN = (N + 255) / 256;
    int nbScan = (N + 1023) / 1024;

    k_count_deg<<<tE, 256, 0, stream>>>(dsts, E, deg, slot);
    k_scan1<<<nbScan, 256, 0, stream>>>(deg, N, row_ptr, partials, dinv);
    k_scan2<<<1, 64, 0, stream>>>(partials, nbScan);
    k_scan3<<<tN, 256, 0, stream>>>(row_ptr, partials, N, E);
    k_place<<<tE, 256, 0, stream>>>(srcs, dsts, E, row_ptr, slot, dinv, ew);

    int total4 = N * D / 4;
    k_tobf16<<<(total4 + 255) / 256, 256, 0, stream>>>(x, xh0, total4);

    int aggBlocks = (N + 3) / 4;          // 4 waves (nodes) per 256-thread block
    int gemmBlocks = (N + 63) / 64;

    // activations ping-pong in bf16: xh0 -> xh1 -> xh0 -> xh1; final layer fp32 -> out
    const ushort_t* xin = xh0;
    for (int l = 0; l < NLAYERS; l++) {
        k_aggregate<<<aggBlocks, 256, 0, stream>>>(xin, row_ptr, ew, dinv, s_buf, N);
        bool last = (l == NLAYERS - 1);
        ushort_t* xout = last ? nullptr : ((l & 1) ? xh0 : xh1);
        k_gemm_bias_relu<<<gemmBlocks, 256, 0, stream>>>(
            s_buf, W + (size_t)l * D * D, b + (size_t)l * D,
            last ? out : nullptr, xout, N);
        xin = xout;
    }
}

// Round 7
// 387.174 us; speedup vs baseline: 1.4318x; 1.0747x over previous
//
#include <hip/hip_runtime.h>

#define D 128
#define NLAYERS 4

typedef unsigned short ushort_t;
typedef unsigned int uint_t;
typedef __attribute__((ext_vector_type(8))) short short8;   // 8 bf16 = 4 VGPR
typedef __attribute__((ext_vector_type(4))) float f32x4;    // mfma accumulator

// round-to-nearest-even fp32 -> bf16 (values are finite; NaN path not needed)
__device__ __forceinline__ ushort_t f2bf(float f) {
    uint_t u = __float_as_uint(f);
    u += 0x7FFFu + ((u >> 16) & 1u);
    return (ushort_t)(u >> 16);
}
__device__ __forceinline__ float bf_lo(uint_t u) {  // low ushort -> float
    return __uint_as_float(u << 16);
}
__device__ __forceinline__ float bf_hi(uint_t u) {  // high ushort -> float
    return __uint_as_float(u & 0xFFFF0000u);
}
__device__ __forceinline__ uint_t pack2(float a, float b) {
    return (uint_t)f2bf(a) | ((uint_t)f2bf(b) << 16);
}

// ---------------- CSR build ----------------

__global__ void k_count_deg(const int* __restrict__ dsts, int E,
                            int* __restrict__ deg, int* __restrict__ slot) {
    int i = blockIdx.x * blockDim.x + threadIdx.x;
    if (i < E) slot[i] = atomicAdd(&deg[dsts[i]], 1);
}

// exclusive scan of deg -> row_ptr (1024/block) + dinv computation (fused)
__global__ void k_scan1(const int* __restrict__ deg, int n, int* __restrict__ out,
                        int* __restrict__ partials, float* __restrict__ dinv) {
    __shared__ int wsum[4];
    int tid = threadIdx.x;
    int base = blockIdx.x * 1024 + tid * 4;
    int d0 = (base + 0 < n) ? deg[base + 0] : 0;
    int d1 = (base + 1 < n) ? deg[base + 1] : 0;
    int d2 = (base + 2 < n) ? deg[base + 2] : 0;
    int d3 = (base + 3 < n) ? deg[base + 3] : 0;
    if (base + 0 < n) dinv[base + 0] = rsqrtf((float)(d0 + 1));
    if (base + 1 < n) dinv[base + 1] = rsqrtf((float)(d1 + 1));
    if (base + 2 < n) dinv[base + 2] = rsqrtf((float)(d2 + 1));
    if (base + 3 < n) dinv[base + 3] = rsqrtf((float)(d3 + 1));
    int s = d0 + d1 + d2 + d3;
    int lane = tid & 63;
    int incl = s;
    #pragma unroll
    for (int off = 1; off < 64; off <<= 1) {
        int y = __shfl_up(incl, off);
        if (lane >= off) incl += y;
    }
    int wid = tid >> 6;
    if (lane == 63) wsum[wid] = incl;
    __syncthreads();
    int wprev = 0;
    for (int w = 0; w < wid; w++) wprev += wsum[w];
    int excl = wprev + (incl - s);
    if (base + 0 < n) out[base + 0] = excl;
    if (base + 1 < n) out[base + 1] = excl + d0;
    if (base + 2 < n) out[base + 2] = excl + d0 + d1;
    if (base + 3 < n) out[base + 3] = excl + d0 + d1 + d2;
    if (tid == 255) partials[blockIdx.x] = wprev + incl;
}

__global__ void k_scan2(int* partials, int nb) {
    if (threadIdx.x == 0 && blockIdx.x == 0) {
        int acc = 0;
        for (int i = 0; i < nb; i++) { int t = partials[i]; partials[i] = acc; acc += t; }
    }
}

__global__ void k_scan3(int* __restrict__ row_ptr, const int* __restrict__ partials,
                        int n, int E) {
    int i = blockIdx.x * blockDim.x + threadIdx.x;
    if (i < n) row_ptr[i] += partials[i >> 10];
    if (i == 0) row_ptr[n] = E;
}

// place edges sorted by destination (atomic-free; slot precomputed)
__global__ void k_place(const int* __restrict__ srcs, const int* __restrict__ dsts, int E,
                        const int* __restrict__ row_ptr, const int* __restrict__ slot,
                        const float* __restrict__ dinv, int2* __restrict__ ew) {
    int i = blockIdx.x * blockDim.x + threadIdx.x;
    if (i >= E) return;
    int c = dsts[i], r = srcs[i];
    int pos = row_ptr[c] + slot[i];
    int2 v;
    v.x = r;
    v.y = __float_as_int(dinv[r]);
    ew[pos] = v;
}

// ---------------- W prep: transpose + hi/lo bf16 split ----------------
// Wt_hi/lo are [L][n][k] bf16 so B-fragments are contiguous 16B loads.
__global__ void k_wprep(const float* __restrict__ W, ushort_t* __restrict__ Wt_hi,
                        ushort_t* __restrict__ Wt_lo) {
    int t = blockIdx.x * 256 + threadIdx.x;     // 4*128*128 threads, n fastest
    int l = t >> 14;
    int k = (t >> 7) & 127;
    int nn = t & 127;
    float w = W[((size_t)l << 14) + k * 128 + nn];
    ushort_t hi = f2bf(w);
    float wf = __uint_as_float((uint_t)hi << 16);
    ushort_t lo = f2bf(w - wf);
    size_t o = ((size_t)l << 14) + nn * 128 + k;
    Wt_hi[o] = hi;
    Wt_lo[o] = lo;
}

// ---------------- x (fp32) -> bf16 ----------------
__global__ void k_tobf16(const float* __restrict__ x, ushort_t* __restrict__ xh,
                         int total4) {
    int i = blockIdx.x * blockDim.x + threadIdx.x;
    if (i >= total4) return;
    float4 v = ((const float4*)x)[i];
    uint2 o;
    o.x = pack2(v.x, v.y);
    o.y = pack2(v.z, v.w);
    ((uint2*)xh)[i] = o;
}

// ---------------- per-layer: aggregation s = A_norm * x  (bf16 in/out) ----------------
// one wave per node; 4 edges per load instruction: lane l reads uint4 (16B)
// of edge slot sub=l>>4 at columns t=(l&15)*8. 16 edges (4 loads) in flight.
__global__ __launch_bounds__(256) void k_aggregate(
    const ushort_t* __restrict__ xh, const int* __restrict__ row_ptr,
    const int2* __restrict__ ew, const float* __restrict__ dinv,
    ushort_t* __restrict__ s, int n) {
    int gwave = (blockIdx.x * 256 + threadIdx.x) >> 6;
    if (gwave >= n) return;
    int lane = threadIdx.x & 63;
    int sub = lane >> 4;   // edge slot within group of 4
    int t = lane & 15;     // column group: owns 8 bf16 cols starting at t*8
    int node = gwave;
    float di = dinv[node];

    float acc[8];
    {   // self contribution (weight di, only counted once via sub==0)
        uint4 v = *(const uint4*)(xh + (size_t)node * D + t * 8);
        float w = (sub == 0) ? di : 0.f;
        acc[0] = w * bf_lo(v.x); acc[1] = w * bf_hi(v.x);
        acc[2] = w * bf_lo(v.y); acc[3] = w * bf_hi(v.y);
        acc[4] = w * bf_lo(v.z); acc[5] = w * bf_hi(v.z);
        acc[6] = w * bf_lo(v.w); acc[7] = w * bf_hi(v.w);
    }
    int e = row_ptr[node], end = row_ptr[node + 1];
    // main loop: 16 edges (4 groups) per iteration, 4 gathers in flight
    for (; e + 16 <= end; e += 16) {
        int2 g0 = ew[e + sub];
        int2 g1 = ew[e + 4 + sub];
        int2 g2 = ew[e + 8 + sub];
        int2 g3 = ew[e + 12 + sub];
        uint4 v0 = *(const uint4*)(xh + (size_t)g0.x * D + t * 8);
        uint4 v1 = *(const uint4*)(xh + (size_t)g1.x * D + t * 8);
        uint4 v2 = *(const uint4*)(xh + (size_t)g2.x * D + t * 8);
        uint4 v3 = *(const uint4*)(xh + (size_t)g3.x * D + t * 8);
        float w0 = __int_as_float(g0.y);
        float w1 = __int_as_float(g1.y);
        float w2 = __int_as_float(g2.y);
        float w3 = __int_as_float(g3.y);
        acc[0] += w0 * bf_lo(v0.x); acc[1] += w0 * bf_hi(v0.x);
        acc[2] += w0 * bf_lo(v0.y); acc[3] += w0 * bf_hi(v0.y);
        acc[4] += w0 * bf_lo(v0.z); acc[5] += w0 * bf_hi(v0.z);
        acc[6] += w0 * bf_lo(v0.w); acc[7] += w0 * bf_hi(v0.w);
        acc[0] += w1 * bf_lo(v1.x); acc[1] += w1 * bf_hi(v1.x);
        acc[2] += w1 * bf_lo(v1.y); acc[3] += w1 * bf_hi(v1.y);
        acc[4] += w1 * bf_lo(v1.z); acc[5] += w1 * bf_hi(v1.z);
        acc[6] += w1 * bf_lo(v1.w); acc[7] += w1 * bf_hi(v1.w);
        acc[0] += w2 * bf_lo(v2.x); acc[1] += w2 * bf_hi(v2.x);
        acc[2] += w2 * bf_lo(v2.y); acc[3] += w2 * bf_hi(v2.y);
        acc[4] += w2 * bf_lo(v2.z); acc[5] += w2 * bf_hi(v2.z);
        acc[6] += w2 * bf_lo(v2.w); acc[7] += w2 * bf_hi(v2.w);
        acc[0] += w3 * bf_lo(v3.x); acc[1] += w3 * bf_hi(v3.x);
        acc[2] += w3 * bf_lo(v3.y); acc[3] += w3 * bf_hi(v3.y);
        acc[4] += w3 * bf_lo(v3.z); acc[5] += w3 * bf_hi(v3.z);
        acc[6] += w3 * bf_lo(v3.w); acc[7] += w3 * bf_hi(v3.w);
    }
    // tail: 1 group (up to 4 edges) per iteration, clamped
    for (; e < end; e += 4) {
        int rem = end - e;                      // >= 1
        int k = (sub < rem) ? sub : 0;          // clamp to a valid edge
        int2 g = ew[e + k];
        float w = (sub < rem) ? __int_as_float(g.y) : 0.f;
        uint4 v = *(const uint4*)(xh + (size_t)g.x * D + t * 8);
        acc[0] += w * bf_lo(v.x); acc[1] += w * bf_hi(v.x);
        acc[2] += w * bf_lo(v.y); acc[3] += w * bf_hi(v.y);
        acc[4] += w * bf_lo(v.z); acc[5] += w * bf_hi(v.z);
        acc[6] += w * bf_lo(v.w); acc[7] += w * bf_hi(v.w);
    }
    // combine the 4 edge slots
    #pragma unroll
    for (int q = 0; q < 8; q++) {
        acc[q] += __shfl_xor(acc[q], 16);
        acc[q] += __shfl_xor(acc[q], 32);
    }
    if (sub == 0) {
        ushort_t* dst = s + (size_t)node * D + t * 8;
        uint4 o;
        o.x = pack2(di * acc[0], di * acc[1]);
        o.y = pack2(di * acc[2], di * acc[3]);
        o.z = pack2(di * acc[4], di * acc[5]);
        o.w = pack2(di * acc[6], di * acc[7]);
        *(uint4*)dst = o;
    }
}

// ---------------- per-layer: out = relu(A @ W + b), MFMA bf16 ----------------
// A [n][128] bf16 from global; W as Wt_hi/lo [n][k] bf16 (hi/lo split keeps
// weight error at fp32 level). Block = 256 thr = 4 waves; wave owns 32 rows.
// mfma_f32_16x16x32_bf16 layouts: A row=lane&15, k=(lane>>4)*8+j;
// B col=lane&15, same k; C col=lane&15, row=(lane>>4)*4+reg.
__global__ __launch_bounds__(256) void k_gemm_mfma(
    const ushort_t* __restrict__ A, const ushort_t* __restrict__ Wt_hi,
    const ushort_t* __restrict__ Wt_lo, const float* __restrict__ bias,
    float* __restrict__ out_f32, ushort_t* __restrict__ out_bf, int n) {
    int tid = threadIdx.x;
    int wave = tid >> 6;
    int lane = tid & 63;
    int lg = lane >> 4;      // k-group / C row-group
    int lr = lane & 15;      // A row / B,C col
    int base_row = blockIdx.x * 128 + wave * 32;

    // A fragments: 2 strips x 4 k-steps, 16B contiguous loads
    short8 a[2][4];
    #pragma unroll
    for (int st = 0; st < 2; st++) {
        int r = base_row + st * 16 + lr;
        if (r > n - 1) r = n - 1;
        const ushort_t* ap = A + (size_t)r * D + lg * 8;
        #pragma unroll
        for (int k0 = 0; k0 < 4; k0++)
            a[st][k0] = *(const short8*)(ap + k0 * 32);
    }

    f32x4 acc[2][8];
    #pragma unroll
    for (int st = 0; st < 2; st++)
        #pragma unroll
        for (int nt = 0; nt < 8; nt++)
            acc[st][nt] = (f32x4){0.f, 0.f, 0.f, 0.f};

    #pragma unroll
    for (int nt = 0; nt < 8; nt++) {
        const ushort_t* wh = Wt_hi + (size_t)(nt * 16 + lr) * D + lg * 8;
        const ushort_t* wl = Wt_lo + (size_t)(nt * 16 + lr) * D + lg * 8;
        #pragma unroll
        for (int k0 = 0; k0 < 4; k0++) {
            short8 bh = *(const short8*)(wh + k0 * 32);
            short8 bl = *(const short8*)(wl + k0 * 32);
            acc[0][nt] = __builtin_amdgcn_mfma_f32_16x16x32_bf16(a[0][k0], bh, acc[0][nt], 0, 0, 0);
            acc[0][nt] = __builtin_amdgcn_mfma_f32_16x16x32_bf16(a[0][k0], bl, acc[0][nt], 0, 0, 0);
            acc[1][nt] = __builtin_amdgcn_mfma_f32_16x16x32_bf16(a[1][k0], bh, acc[1][nt], 0, 0, 0);
            acc[1][nt] = __builtin_amdgcn_mfma_f32_16x16x32_bf16(a[1][k0], bl, acc[1][nt], 0, 0, 0);
        }
    }

    #pragma unroll
    for (int nt = 0; nt < 8; nt++) {
        int col = nt * 16 + lr;
        float bv = bias[col];
        #pragma unroll
        for (int st = 0; st < 2; st++) {
            #pragma unroll
            for (int r = 0; r < 4; r++) {
                int grow = base_row + st * 16 + lg * 4 + r;
                if (grow < n) {
                    float o = fmaxf(acc[st][nt][r] + bv, 0.f);
                    if (out_bf) out_bf[(size_t)grow * D + col] = f2bf(o);
                    else out_f32[(size_t)grow * D + col] = o;
                }
            }
        }
    }
}

// ---------------- host launch ----------------

extern "C" void kernel_launch(void* const* d_in, const int* in_sizes, int n_in,
                              void* d_out, int out_size, void* d_ws, size_t ws_size,
                              hipStream_t stream) {
    const float* x   = (const float*)d_in[0];
    const int* eidx  = (const int*)d_in[1];
    const float* W   = (const float*)d_in[4];
    const float* b   = (const float*)d_in[5];
    float* out       = (float*)d_out;

    const int N = in_sizes[0] / D;
    const int E = in_sizes[1] / 2;
    const int* srcs = eidx;       // edge_index[0]
    const int* dsts = eidx + E;   // edge_index[1]

    // workspace carve-up (512B aligned)
    char* ws = (char*)d_ws;
    size_t off = 0;
    auto alloc = [&](size_t bytes) -> void* {
        void* p = ws + off;
        off = (off + bytes + 511) & ~(size_t)511;
        return p;
    };
    int*      deg      = (int*)alloc((size_t)N * 4);
    float*    dinv     = (float*)alloc((size_t)N * 4);
    int*      row_ptr  = (int*)alloc((size_t)(N + 1) * 4);
    int*      partials = (int*)alloc(256 * 4);
    int2*     ew       = (int2*)alloc((size_t)E * 8);
    ushort_t* s_buf    = (ushort_t*)alloc((size_t)N * D * 2);   // bf16 now
    ushort_t* xh0      = (ushort_t*)alloc((size_t)N * D * 2);
    ushort_t* xh1      = (ushort_t*)alloc((size_t)N * D * 2);
    ushort_t* wt_hi    = (ushort_t*)alloc((size_t)NLAYERS * D * D * 2);
    ushort_t* wt_lo    = (ushort_t*)alloc((size_t)NLAYERS * D * D * 2);
    // slot[] only live during CSR build, before first aggregate writes s_buf
    int*      slot     = (int*)s_buf;   // E*4 = 3.2MB <= N*D*2 = 12.8MB
    (void)ws_size; (void)n_in; (void)out_size;

    hipMemsetAsync(deg, 0, (size_t)N * 4, stream);

    int tE = (E + 255) / 256;
    int tN = (N + 255) / 256;
    int nbScan = (N + 1023) / 1024;

    k_count_deg<<<tE, 256, 0, stream>>>(dsts, E, deg, slot);
    k_scan1<<<nbScan, 256, 0, stream>>>(deg, N, row_ptr, partials, dinv);
    k_scan2<<<1, 64, 0, stream>>>(partials, nbScan);
    k_scan3<<<tN, 256, 0, stream>>>(row_ptr, partials, N, E);
    k_place<<<tE, 256, 0, stream>>>(srcs, dsts, E, row_ptr, slot, dinv, ew);
    k_wprep<<<(NLAYERS * D * D) / 256, 256, 0, stream>>>(W, wt_hi, wt_lo);

    int total4 = N * D / 4;
    k_tobf16<<<(total4 + 255) / 256, 256, 0, stream>>>(x, xh0, total4);

    int aggBlocks = (N + 3) / 4;            // 4 waves (nodes) per 256-thread block
    int gemmBlocks = (N + 127) / 128;       // 128 rows per block (4 waves x 32)

    // activations ping-pong in bf16: xh0 -> xh1 -> xh0 -> xh1; final layer fp32 -> out
    const ushort_t* xin = xh0;
    for (int l = 0; l < NLAYERS; l++) {
        k_aggregate<<<aggBlocks, 256, 0, stream>>>(xin, row_ptr, ew, dinv, s_buf, N);
        bool last = (l == NLAYERS - 1);
        ushort_t* xout = last ? nullptr : ((l & 1) ? xh0 : xh1);
        k_gemm_mfma<<<gemmBlocks, 256, 0, stream>>>(
            s_buf, wt_hi + (size_t)l * D * D, wt_lo + (size_t)l * D * D,
            b + (size_t)l * D, last ? out : nullptr, xout, N);
        xin = xout;
    }
}